// Round 9
// baseline (128.045 us; speedup 1.0000x reference)
//
#include <hip/hip_runtime.h>

constexpr int T_TOK = 8192;
constexpr int H_DIM = 2048;
constexpr int E_NUM = 8;
constexpr int L_DIM = 16;

constexpr int KSB   = 16;    // h-slabs of 128
constexpr int NBLK2 = 8;     // sinkhorn blocks
constexpr int BLK2  = 1024;  // sinkhorn threads/block; 8*1024 == T_TOK (1 row/thread)

// workspace layout (float offsets); slab first (8B aligned at 0)
constexpr size_t WS_SLAB = 0;                      // 2*NBLK2*16 u64 = 512 floats
constexpr size_t WS_PB   = 512;                    // KSB * 16 * T floats (8.39 MB)

// ---------------- Kernel 1: grouped logits partials (tile GEMM) ----------------
// 2048 blocks = (tset 0..127)<<4 | (sb 0..15). Tile: 64 tokens x 16 L x 128 h.
// x-tile staged with BOTH-SIDES XOR swizzle (G21): LDS writes lane-linear
// (conflict-free ds_write_b128), global source pre-swizzled per lane,
// reads apply the same involution -> 2-way banks (free).
// Partials written TRANSPOSED pbT[sb][l][t] so k2's prologue coalesces.
__global__ __launch_bounds__(256) void k1a(const float* __restrict__ x,
                                           const float* __restrict__ w1,
                                           const int* __restrict__ tpe,
                                           float* __restrict__ pbT) {
    const int tid  = threadIdx.x;
    const int sb   = blockIdx.x & 15;
    const int tset = blockIdx.x >> 4;
    const int tokg = tid >> 4;          // 0..15
    const int lg   = (tid >> 2) & 3;    // 0..3
    const int ksub = tid & 3;           // 0..3
    const int h0   = sb * 128;

    __shared__ float xbuf[8192];        // [64 rows][32 f4-chunks] swizzled
    __shared__ float wbuf[128 * 20];    // [h][20] pad: <=2-way on reads

    // expert id (64-token tile lies within one expert group; boundaries @1024)
    int e = 0;
    {
        const int tok0 = tset * 64;
        int accum = 0;
        #pragma unroll
        for (int i = 0; i < E_NUM - 1; ++i) {
            accum += tpe[i];
            e += (tok0 >= accum) ? 1 : 0;
        }
    }
    const int e0 = __builtin_amdgcn_readfirstlane(e);

    // ---- issue w loads (2 f4/thread) and x loads (8 f4/thread, swizzled src) ----
    const float4* wsrc =
        reinterpret_cast<const float4*>(w1 + ((size_t)e0 * H_DIM + h0) * L_DIM);
    const float4 wv0 = wsrc[tid];
    const float4 wv1 = wsrc[256 + tid];

    float4 xv[8];
    #pragma unroll
    for (int k = 0; k < 8; ++k) {
        const int slot = tid + 256 * k;                  // linear f4 slot 0..2047
        const int row  = slot >> 5;                      // 0..63
        const int pc   = slot & 31;                      // physical chunk
        const int lc   = pc ^ (((row >> 2) & 3) << 1);   // logical chunk (involution)
        xv[k] = *reinterpret_cast<const float4*>(
            x + (size_t)(tset * 64 + row) * H_DIM + h0 + 4 * lc);
    }

    // ---- LDS writes: w padded, x lane-linear (conflict-free) ----
    {
        const int h  = tid >> 2;
        const int l0 = (tid & 3) * 4;
        *reinterpret_cast<float4*>(&wbuf[h * 20 + l0])        = wv0;
        *reinterpret_cast<float4*>(&wbuf[(64 + h) * 20 + l0]) = wv1;
    }
    #pragma unroll
    for (int k = 0; k < 8; ++k)
        *reinterpret_cast<float4*>(&xbuf[(tid + 256 * k) * 4]) = xv[k];

    __syncthreads();

    // ---- compute: acc[4 tok][4 l]; x read offset = 4*kk + 16*(s^tb) ----
    float acc[4][4];
    #pragma unroll
    for (int r = 0; r < 4; ++r)
        #pragma unroll
        for (int q = 0; q < 4; ++q) acc[r][q] = 0.f;

    const int tb = (tokg >> 1) & 1;
    const int kk = ksub ^ ((tokg & 1) << 1);
    const float* xrs[4];
    #pragma unroll
    for (int r = 0; r < 4; ++r)
        xrs[r] = &xbuf[(4 * tokg + r) * 128 + 4 * kk];
    const float* wb = &wbuf[(4 * ksub) * 20 + 4 * lg];

    #pragma unroll
    for (int s = 0; s < 8; ++s) {
        const int xo = ((s ^ tb) << 4);                  // (s^tb)*16 floats
        float4 xr[4], wj[4];
        #pragma unroll
        for (int r = 0; r < 4; ++r)
            xr[r] = *reinterpret_cast<const float4*>(xrs[r] + xo);
        #pragma unroll
        for (int j = 0; j < 4; ++j)
            wj[j] = *reinterpret_cast<const float4*>(wb + 320 * s + 20 * j);
        #pragma unroll
        for (int r = 0; r < 4; ++r) {
            const float xs[4] = {xr[r].x, xr[r].y, xr[r].z, xr[r].w};
            #pragma unroll
            for (int j = 0; j < 4; ++j) {
                acc[r][0] += xs[j] * wj[j].x;
                acc[r][1] += xs[j] * wj[j].y;
                acc[r][2] += xs[j] * wj[j].z;
                acc[r][3] += xs[j] * wj[j].w;
            }
        }
    }

    // ---- reduce over ksub via LDS overlay ----
    __syncthreads();   // done reading xbuf; overlay red[4][64][17]
    float* red = xbuf;
    #pragma unroll
    for (int r = 0; r < 4; ++r)
        #pragma unroll
        for (int q = 0; q < 4; ++q)
            red[ksub * 1088 + (4 * tokg + r) * 17 + 4 * lg + q] = acc[r][q];
    __syncthreads();

    // ---- write pbT[sb][l][t] : thread owns (l = tid>>4, 4 rows at 4*(tid&15)) ----
    {
        const int l  = tid >> 4;
        const int cc = tid & 15;
        float4 o;
        float* op = &o.x;
        #pragma unroll
        for (int j = 0; j < 4; ++j) {
            const int tok = 4 * cc + j;
            op[j] = red[0 * 1088 + tok * 17 + l] + red[1 * 1088 + tok * 17 + l]
                  + red[2 * 1088 + tok * 17 + l] + red[3 * 1088 + tok * 17 + l];
        }
        *reinterpret_cast<float4*>(
            &pbT[((size_t)(sb * 16 + l) << 13) + tset * 64 + 4 * cc]) = o;
    }
}

// ---------------- Kernel 2: Sinkhorn + fused finalize ----------------
// R6's measured-fast structure (8 blocks x 1024 thr, 1 row/thread, 16
// waves/CU hide shuffle/poll latency; 0.77us/iter) + R7's coalesced pbT
// prologue (row-contiguous loads). One-sided tagged parity slab sync:
// publish by tid<16, 128-lane parallel spin (one entry each), fixed-order
// sums -> deterministic, bitwise-stable across replays.
__global__ __launch_bounds__(1024) void k_sinkhorn(float* __restrict__ ws,
                                                   float* __restrict__ out) {
    unsigned long long* slab = reinterpret_cast<unsigned long long*>(ws + WS_SLAB);
    const float* pbT = ws + WS_PB;

    const int tid  = threadIdx.x;
    const int blk  = blockIdx.x;
    const int t    = blk * BLK2 + tid;          // this thread's row
    const int wv   = tid >> 6;                  // 0..15
    const int lane = tid & 63;

    // prologue: c[l] = sum over 16 slabs of pbT[sb][l][t]; coalesced (stride-1
    // across tid within each (sb,l) plane), 256 independent scalar loads.
    float c[16];
    #pragma unroll
    for (int l = 0; l < 16; ++l) c[l] = 0.f;
    #pragma unroll
    for (int sb = 0; sb < KSB; ++sb) {
        #pragma unroll
        for (int l = 0; l < 16; ++l)
            c[l] += pbT[((size_t)(sb * 16 + l) << 13) + t];
    }
    #pragma unroll
    for (int l = 0; l < 16; ++l) c[l] = expf(c[l]);

    float d1[16];
    #pragma unroll
    for (int l = 0; l < 16; ++l) d1[l] = 1.f;

    __shared__ float s_wpart[16][16];
    __shared__ float s_bpart[NBLK2][16];
    __shared__ float s_d1n[16];

    float d0n = 0.f;
    float err = 1e9f;
    int it = 0;

    do {
        // d0n = (1/T) / (cost @ d1 + eps)
        float s = 0.f;
        #pragma unroll
        for (int l = 0; l < 16; ++l) s += c[l] * d1[l];
        d0n = (1.f / (float)T_TOK) / (s + 1e-8f);

        // per-lane column partials
        float con[16];
        #pragma unroll
        for (int l = 0; l < 16; ++l) con[l] = d0n * c[l];
        #pragma unroll
        for (int m = 1; m < 64; m <<= 1) {
            #pragma unroll
            for (int l = 0; l < 16; ++l) con[l] += __shfl_xor(con[l], m, 64);
        }
        if (lane == 0) {
            #pragma unroll
            for (int l = 0; l < 16; ++l) s_wpart[wv][l] = con[l];
        }
        __syncthreads();

        const int p = it & 1;
        if (tid < 16) {
            float bs = 0.f;
            #pragma unroll
            for (int w = 0; w < 16; ++w) bs += s_wpart[w][tid];
            const unsigned long long pv =
                ((unsigned long long)(unsigned)it << 32) |
                (unsigned long long)__float_as_uint(bs);
            __hip_atomic_store(&slab[(size_t)p * 128 + blk * 16 + tid],
                               pv, __ATOMIC_RELAXED, __HIP_MEMORY_SCOPE_AGENT);
        }
        if (tid < NBLK2 * 16) {
            // lane-parallel spin: ONE entry per lane
            unsigned long long v;
            int spins = 0;
            do {
                v = __hip_atomic_load(&slab[(size_t)p * 128 + tid],
                                      __ATOMIC_RELAXED, __HIP_MEMORY_SCOPE_AGENT);
            } while ((unsigned)(v >> 32) != (unsigned)it && ++spins < (1 << 22));
            s_bpart[tid >> 4][tid & 15] = __uint_as_float((unsigned)(v & 0xffffffffull));
        }
        __syncthreads();

        if (tid < 16) {
            float tot = 0.f;
            #pragma unroll
            for (int b = 0; b < NBLK2; ++b) tot += s_bpart[b][tid];
            s_d1n[tid] = (1.f / (float)L_DIM) / (tot + 1e-8f);
        }
        __syncthreads();

        float esum = 0.f;
        #pragma unroll
        for (int l = 0; l < 16; ++l) {
            const float nv = s_d1n[l];
            esum += fabsf(d1[l] - nv);
            d1[l] = nv;
        }
        err = esum * (1.f / 16.f);
        ++it;
    } while (err > 1e-4f && it < 512);

    // fused finalize: top-2 of (d1*c)*d0n, softmax-gather (ref op order)
    {
        float v1 = -__builtin_inff(), v2 = -__builtin_inff();
        float a1 = 0.f, a2 = 0.f;
        int   i1 = 0, i2 = 0;
        float ssum = 0.f;
        #pragma unroll
        for (int l = 0; l < 16; ++l) {
            ssum += c[l];
            const float nv = (d1[l] * c[l]) * d0n;
            if (nv > v1) { v2 = v1; i2 = i1; a2 = a1; v1 = nv; i1 = l; a1 = c[l]; }
            else if (nv > v2) { v2 = nv; i2 = l; a2 = c[l]; }
        }
        out[(size_t)t * 2 + 0] = a1 / ssum;
        out[(size_t)t * 2 + 1] = a2 / ssum;
        out[(size_t)2 * T_TOK + (size_t)t * 2 + 0] = (float)i1;
        out[(size_t)2 * T_TOK + (size_t)t * 2 + 1] = (float)i2;
    }
}

extern "C" void kernel_launch(void* const* d_in, const int* in_sizes, int n_in,
                              void* d_out, int out_size, void* d_ws, size_t ws_size,
                              hipStream_t stream) {
    const float* x   = (const float*)d_in[0];
    const float* w1  = (const float*)d_in[1];
    const int*   tpe = (const int*)d_in[2];
    float* ws  = (float*)d_ws;
    float* out = (float*)d_out;

    // K1: tile-GEMM logits partials, transposed output
    k1a<<<dim3(128 * KSB), dim3(256), 0, stream>>>(x, w1, tpe, ws + WS_PB);

    // K2: coalesced pbT prologue + sinkhorn + finalize (cooperative for
    // co-residency; sync is the one-sided tagged slab, no grid.sync)
    {
        void* args[] = { (void*)&ws, (void*)&out };
        hipLaunchCooperativeKernel((void*)k_sinkhorn, dim3(NBLK2), dim3(BLK2),
                                   args, 0, stream);
    }
}

// Round 10
// 85.047 us; speedup vs baseline: 1.5056x; 1.5056x over previous
//
#include <hip/hip_runtime.h>

constexpr int T_TOK = 8192;
constexpr int H_DIM = 2048;
constexpr int E_NUM = 8;
constexpr int L_DIM = 16;

constexpr int KSB   = 16;    // h-slabs of 128
constexpr int NBLK2 = 8;     // sinkhorn blocks
constexpr int BLK2  = 256;   // sinkhorn threads/block; 8*256*4 rows == T_TOK

// workspace layout (float offsets); slab first (8B aligned at 0)
constexpr size_t WS_SLAB = 0;                      // 2*NBLK2*16 u64 = 512 floats
constexpr size_t WS_PB   = 512;                    // KSB * 16 * T floats (8.39 MB)

// ---------------- Kernel 1: grouped logits partials (tile GEMM) ----------------
// 2048 blocks = (tset 0..127)<<4 | (sb 0..15). Tile: 64 tokens x 16 L x 128 h.
// x staged in LDS with the R7-proven both-sides XOR swizzle. w is NOT staged:
// the 8 KB w-slab is L1-resident, read directly from global in the inner loop
// (4 x 64B lines per instr) — deletes wbuf (LDS 43->32 KB, 4 blocks/CU) and
// halves LDS-read issue pressure (was the co-binding resource with HBM).
// Partials written TRANSPOSED pbT[sb][l][t] so k2's prologue coalesces.
__global__ __launch_bounds__(256) void k1a(const float* __restrict__ x,
                                           const float* __restrict__ w1,
                                           const int* __restrict__ tpe,
                                           float* __restrict__ pbT) {
    const int tid  = threadIdx.x;
    const int sb   = blockIdx.x & 15;
    const int tset = blockIdx.x >> 4;
    const int tokg = tid >> 4;          // 0..15
    const int lg   = (tid >> 2) & 3;    // 0..3
    const int ksub = tid & 3;           // 0..3
    const int h0   = sb * 128;

    __shared__ float xbuf[8192];        // [64 rows][32 f4-chunks] swizzled

    // expert id (64-token tile lies within one expert group; boundaries @1024)
    int e = 0;
    {
        const int tok0 = tset * 64;
        int accum = 0;
        #pragma unroll
        for (int i = 0; i < E_NUM - 1; ++i) {
            accum += tpe[i];
            e += (tok0 >= accum) ? 1 : 0;
        }
    }
    const int e0 = __builtin_amdgcn_readfirstlane(e);

    // ---- x loads (8 f4/thread, swizzled src; same cache lines, coalesced) ----
    float4 xv[8];
    #pragma unroll
    for (int k = 0; k < 8; ++k) {
        const int slot = tid + 256 * k;                  // linear f4 slot 0..2047
        const int row  = slot >> 5;                      // 0..63
        const int pc   = slot & 31;                      // physical chunk
        const int lc   = pc ^ (((row >> 2) & 3) << 1);   // logical chunk (involution)
        xv[k] = *reinterpret_cast<const float4*>(
            x + (size_t)(tset * 64 + row) * H_DIM + h0 + 4 * lc);
    }
    #pragma unroll
    for (int k = 0; k < 8; ++k)
        *reinterpret_cast<float4*>(&xbuf[(tid + 256 * k) * 4]) = xv[k];

    __syncthreads();

    // ---- compute: acc[4 tok][4 l]; x from LDS (swizzled), w from global/L1 ----
    float acc[4][4];
    #pragma unroll
    for (int r = 0; r < 4; ++r)
        #pragma unroll
        for (int q = 0; q < 4; ++q) acc[r][q] = 0.f;

    const int tb = (tokg >> 1) & 1;
    const int kk = ksub ^ ((tokg & 1) << 1);
    const float* xrs[4];
    #pragma unroll
    for (int r = 0; r < 4; ++r)
        xrs[r] = &xbuf[(4 * tokg + r) * 128 + 4 * kk];
    // w row h = h0 + 4*ksub + 16*s + j, cols 4*lg..+3  (8 KB slab, L1-resident)
    const float* __restrict__ wgt =
        w1 + ((size_t)e0 * H_DIM + h0 + 4 * ksub) * L_DIM + 4 * lg;

    #pragma unroll
    for (int s = 0; s < 8; ++s) {
        const int xo = ((s ^ tb) << 4);                  // (s^tb)*16 floats
        float4 xr[4], wj[4];
        #pragma unroll
        for (int r = 0; r < 4; ++r)
            xr[r] = *reinterpret_cast<const float4*>(xrs[r] + xo);
        #pragma unroll
        for (int j = 0; j < 4; ++j)
            wj[j] = *reinterpret_cast<const float4*>(wgt + 256 * s + 16 * j);
        #pragma unroll
        for (int r = 0; r < 4; ++r) {
            const float xs[4] = {xr[r].x, xr[r].y, xr[r].z, xr[r].w};
            #pragma unroll
            for (int j = 0; j < 4; ++j) {
                acc[r][0] += xs[j] * wj[j].x;
                acc[r][1] += xs[j] * wj[j].y;
                acc[r][2] += xs[j] * wj[j].z;
                acc[r][3] += xs[j] * wj[j].w;
            }
        }
    }

    // ---- reduce over ksub via LDS overlay ----
    __syncthreads();   // done reading xbuf; overlay red[4][64][17]
    float* red = xbuf;
    #pragma unroll
    for (int r = 0; r < 4; ++r)
        #pragma unroll
        for (int q = 0; q < 4; ++q)
            red[ksub * 1088 + (4 * tokg + r) * 17 + 4 * lg + q] = acc[r][q];
    __syncthreads();

    // ---- write pbT[sb][l][t] : thread owns (l = tid>>4, 4 rows at 4*(tid&15)) ----
    {
        const int l  = tid >> 4;
        const int cc = tid & 15;
        float4 o;
        float* op = &o.x;
        #pragma unroll
        for (int j = 0; j < 4; ++j) {
            const int tok = 4 * cc + j;
            op[j] = red[0 * 1088 + tok * 17 + l] + red[1 * 1088 + tok * 17 + l]
                  + red[2 * 1088 + tok * 17 + l] + red[3 * 1088 + tok * 17 + l];
        }
        *reinterpret_cast<float4*>(
            &pbT[((size_t)(sb * 16 + l) << 13) + tset * 64 + 4 * cc]) = o;
    }
}

// ---------------- Kernel 2: Sinkhorn + fused finalize (R8 verbatim) ----------------
// 8 blocks x 256 thr, 4 contiguous rows/thread (c[4][16] in VGPRs).
// Prologue: coalesced pbT float4 reads. Per iter: dots -> butterfly ->
// s_wpart -> barrier -> 16 owners publish tagged u64; 128 lanes spin ONE
// entry each -> s_bpart -> barrier -> 16 owners sum 8 + write s_d1n ->
// barrier. Deterministic fixed-order sums, bitwise-stable replays.
__global__ __launch_bounds__(256) void k_sinkhorn(float* __restrict__ ws,
                                                  float* __restrict__ out) {
    unsigned long long* slab = reinterpret_cast<unsigned long long*>(ws + WS_SLAB);
    const float* pbT = ws + WS_PB;

    const int tid  = threadIdx.x;
    const int blk  = blockIdx.x;
    const int wv   = tid >> 6;                  // 0..3
    const int lane = tid & 63;

    // prologue: c[i][l] for rows blk*1024 + 4*tid + i
    float c[4][16];
    #pragma unroll
    for (int i = 0; i < 4; ++i)
        #pragma unroll
        for (int l = 0; l < 16; ++l) c[i][l] = 0.f;

    #pragma unroll
    for (int sb = 0; sb < KSB; ++sb) {
        #pragma unroll
        for (int l = 0; l < 16; ++l) {
            const float4 v = *reinterpret_cast<const float4*>(
                pbT + ((size_t)(sb * 16 + l) << 13) + blk * 1024 + 4 * tid);
            c[0][l] += v.x; c[1][l] += v.y; c[2][l] += v.z; c[3][l] += v.w;
        }
    }
    #pragma unroll
    for (int i = 0; i < 4; ++i)
        #pragma unroll
        for (int l = 0; l < 16; ++l) c[i][l] = expf(c[i][l]);

    float d1[16];
    #pragma unroll
    for (int l = 0; l < 16; ++l) d1[l] = 1.f;

    __shared__ float s_wpart[4][16];
    __shared__ float s_bpart[NBLK2][16];
    __shared__ float s_d1n[16];

    float d0n[4] = {0.f, 0.f, 0.f, 0.f};
    float err = 1e9f;
    int it = 0;

    do {
        // d0n per row
        #pragma unroll
        for (int i = 0; i < 4; ++i) {
            float s = 0.f;
            #pragma unroll
            for (int l = 0; l < 16; ++l) s += c[i][l] * d1[l];
            d0n[i] = (1.f / (float)T_TOK) / (s + 1e-8f);
        }

        // per-lane column partials over the 4 rows
        float con[16];
        #pragma unroll
        for (int l = 0; l < 16; ++l)
            con[l] = d0n[0] * c[0][l] + d0n[1] * c[1][l]
                   + d0n[2] * c[2][l] + d0n[3] * c[3][l];
        #pragma unroll
        for (int m = 1; m < 64; m <<= 1) {
            #pragma unroll
            for (int l = 0; l < 16; ++l) con[l] += __shfl_xor(con[l], m, 64);
        }
        if (lane == 0) {
            #pragma unroll
            for (int l = 0; l < 16; ++l) s_wpart[wv][l] = con[l];
        }
        __syncthreads();

        const int p = it & 1;
        if (tid < 16) {
            const float bs = s_wpart[0][tid] + s_wpart[1][tid]
                           + s_wpart[2][tid] + s_wpart[3][tid];
            const unsigned long long pv =
                ((unsigned long long)(unsigned)it << 32) |
                (unsigned long long)__float_as_uint(bs);
            __hip_atomic_store(&slab[(size_t)p * 128 + blk * 16 + tid],
                               pv, __ATOMIC_RELAXED, __HIP_MEMORY_SCOPE_AGENT);
        }
        if (tid < NBLK2 * 16) {
            // lane-parallel spin: ONE entry per lane
            unsigned long long v;
            int spins = 0;
            do {
                v = __hip_atomic_load(&slab[(size_t)p * 128 + tid],
                                      __ATOMIC_RELAXED, __HIP_MEMORY_SCOPE_AGENT);
            } while ((unsigned)(v >> 32) != (unsigned)it && ++spins < (1 << 22));
            s_bpart[tid >> 4][tid & 15] = __uint_as_float((unsigned)(v & 0xffffffffull));
        }
        __syncthreads();

        if (tid < 16) {
            float tot = 0.f;
            #pragma unroll
            for (int b = 0; b < NBLK2; ++b) tot += s_bpart[b][tid];
            s_d1n[tid] = (1.f / (float)L_DIM) / (tot + 1e-8f);
        }
        __syncthreads();

        float esum = 0.f;
        #pragma unroll
        for (int l = 0; l < 16; ++l) {
            const float nv = s_d1n[l];
            esum += fabsf(d1[l] - nv);
            d1[l] = nv;
        }
        err = esum * (1.f / 16.f);
        ++it;
    } while (err > 1e-4f && it < 512);

    // fused finalize per row: top-2 of (d1*c)*d0n, softmax-gather (ref op order)
    #pragma unroll
    for (int i = 0; i < 4; ++i) {
        const int t = blk * 1024 + 4 * tid + i;
        float v1 = -__builtin_inff(), v2 = -__builtin_inff();
        float a1 = 0.f, a2 = 0.f;
        int   i1 = 0, i2 = 0;
        float ssum = 0.f;
        #pragma unroll
        for (int l = 0; l < 16; ++l) {
            ssum += c[i][l];
            const float nv = (d1[l] * c[i][l]) * d0n[i];
            if (nv > v1) { v2 = v1; i2 = i1; a2 = a1; v1 = nv; i1 = l; a1 = c[i][l]; }
            else if (nv > v2) { v2 = nv; i2 = l; a2 = c[i][l]; }
        }
        out[(size_t)t * 2 + 0] = a1 / ssum;
        out[(size_t)t * 2 + 1] = a2 / ssum;
        out[(size_t)2 * T_TOK + (size_t)t * 2 + 0] = (float)i1;
        out[(size_t)2 * T_TOK + (size_t)t * 2 + 1] = (float)i2;
    }
}

extern "C" void kernel_launch(void* const* d_in, const int* in_sizes, int n_in,
                              void* d_out, int out_size, void* d_ws, size_t ws_size,
                              hipStream_t stream) {
    const float* x   = (const float*)d_in[0];
    const float* w1  = (const float*)d_in[1];
    const int*   tpe = (const int*)d_in[2];
    float* ws  = (float*)d_ws;
    float* out = (float*)d_out;

    // K1: tile-GEMM logits partials, transposed output (w from global/L1)
    k1a<<<dim3(128 * KSB), dim3(256), 0, stream>>>(x, w1, tpe, ws + WS_PB);

    // K2: coalesced pbT prologue + sinkhorn + finalize (cooperative for
    // co-residency; sync is the one-sided tagged slab, no grid.sync)
    {
        void* args[] = { (void*)&ws, (void*)&out };
        hipLaunchCooperativeKernel((void*)k_sinkhorn, dim3(NBLK2), dim3(BLK2),
                                   args, 0, stream);
    }
}

// Round 11
// 61.887 us; speedup vs baseline: 2.0690x; 1.3742x over previous
//
#include <hip/hip_runtime.h>

constexpr int T_TOK = 8192;
constexpr int H_DIM = 2048;
constexpr int E_NUM = 8;
constexpr int L_DIM = 16;

constexpr int KSB   = 8;     // h-slabs of 256 (two 128-h passes per block)
constexpr int NBLK2 = 8;     // sinkhorn blocks
constexpr int BLK2  = 256;   // sinkhorn threads/block; 8*256*4 rows == T_TOK

// workspace layout (float offsets); slab first (8B aligned at 0)
constexpr size_t WS_SLAB = 0;                      // 2*NBLK2*16 u64 = 512 floats
constexpr size_t WS_PB   = 512;                    // KSB * 16 * T floats (4.2 MB)

// ---------------- Kernel 1: grouped logits partials (tile GEMM) ----------------
// 1024 blocks = (tset 0..127)<<3 | (sb 0..7). Tile: 64 tokens x 16 L x 256 h,
// processed as TWO sequential 128-h passes (R8's proven stage+compute body)
// with register-carried acc — halves pb traffic and epilogue cost vs KSB=16.
// x-tile staged with both-sides XOR swizzle (lane-linear ds_write_b128,
// pre-swizzled global src, same involution on reads -> 2-way banks = free).
// Partials written TRANSPOSED pbT[sb][l][t] so k2's prologue coalesces.
__global__ __launch_bounds__(256) void k1a(const float* __restrict__ x,
                                           const float* __restrict__ w1,
                                           const int* __restrict__ tpe,
                                           float* __restrict__ pbT) {
    const int tid  = threadIdx.x;
    const int sb   = blockIdx.x & 7;
    const int tset = blockIdx.x >> 3;
    const int tokg = tid >> 4;          // 0..15
    const int lg   = (tid >> 2) & 3;    // 0..3
    const int ksub = tid & 3;           // 0..3

    __shared__ float xbuf[8192];        // [64 rows][32 f4-chunks] swizzled
    __shared__ float wbuf[128 * 20];    // [h][20] pad: <=2-way on reads

    // expert id (64-token tile lies within one expert group; boundaries @1024)
    int e = 0;
    {
        const int tok0 = tset * 64;
        int accum = 0;
        #pragma unroll
        for (int i = 0; i < E_NUM - 1; ++i) {
            accum += tpe[i];
            e += (tok0 >= accum) ? 1 : 0;
        }
    }
    const int e0 = __builtin_amdgcn_readfirstlane(e);

    float acc[4][4];
    #pragma unroll
    for (int r = 0; r < 4; ++r)
        #pragma unroll
        for (int q = 0; q < 4; ++q) acc[r][q] = 0.f;

    // LDS read geometry (p-independent): same involution as the staging side
    const int tb = (tokg >> 1) & 1;
    const int kk = ksub ^ ((tokg & 1) << 1);
    const float* xrs[4];
    #pragma unroll
    for (int r = 0; r < 4; ++r)
        xrs[r] = &xbuf[(4 * tokg + r) * 128 + 4 * kk];
    const float* wb = &wbuf[(4 * ksub) * 20 + 4 * lg];

    #pragma unroll
    for (int p = 0; p < 2; ++p) {
        const int h0 = sb * 256 + p * 128;
        if (p) __syncthreads();   // pass-0 readers done before overwrite

        // ---- issue w loads (2 f4/thread) and x loads (8 f4/thread, swizzled) ----
        const float4* wsrc =
            reinterpret_cast<const float4*>(w1 + ((size_t)e0 * H_DIM + h0) * L_DIM);
        const float4 wv0 = wsrc[tid];
        const float4 wv1 = wsrc[256 + tid];

        float4 xv[8];
        #pragma unroll
        for (int k = 0; k < 8; ++k) {
            const int slot = tid + 256 * k;                  // linear f4 slot
            const int row  = slot >> 5;                      // 0..63
            const int pc   = slot & 31;                      // physical chunk
            const int lc   = pc ^ (((row >> 2) & 3) << 1);   // logical (involution)
            xv[k] = *reinterpret_cast<const float4*>(
                x + (size_t)(tset * 64 + row) * H_DIM + h0 + 4 * lc);
        }

        // ---- LDS writes: w padded, x lane-linear (conflict-free) ----
        {
            const int h  = tid >> 2;
            const int l0 = (tid & 3) * 4;
            *reinterpret_cast<float4*>(&wbuf[h * 20 + l0])        = wv0;
            *reinterpret_cast<float4*>(&wbuf[(64 + h) * 20 + l0]) = wv1;
        }
        #pragma unroll
        for (int k = 0; k < 8; ++k)
            *reinterpret_cast<float4*>(&xbuf[(tid + 256 * k) * 4]) = xv[k];

        __syncthreads();

        // ---- compute: acc[4 tok][4 l]; x offset = 4*kk + 16*(s^tb) ----
        #pragma unroll
        for (int s = 0; s < 8; ++s) {
            const int xo = ((s ^ tb) << 4);
            float4 xr[4], wj[4];
            #pragma unroll
            for (int r = 0; r < 4; ++r)
                xr[r] = *reinterpret_cast<const float4*>(xrs[r] + xo);
            #pragma unroll
            for (int j = 0; j < 4; ++j)
                wj[j] = *reinterpret_cast<const float4*>(wb + 320 * s + 20 * j);
            #pragma unroll
            for (int r = 0; r < 4; ++r) {
                const float xs[4] = {xr[r].x, xr[r].y, xr[r].z, xr[r].w};
                #pragma unroll
                for (int j = 0; j < 4; ++j) {
                    acc[r][0] += xs[j] * wj[j].x;
                    acc[r][1] += xs[j] * wj[j].y;
                    acc[r][2] += xs[j] * wj[j].z;
                    acc[r][3] += xs[j] * wj[j].w;
                }
            }
        }
    }

    // ---- reduce over ksub via LDS overlay ----
    __syncthreads();   // done reading xbuf; overlay red[4][64][17]
    float* red = xbuf;
    #pragma unroll
    for (int r = 0; r < 4; ++r)
        #pragma unroll
        for (int q = 0; q < 4; ++q)
            red[ksub * 1088 + (4 * tokg + r) * 17 + 4 * lg + q] = acc[r][q];
    __syncthreads();

    // ---- write pbT[sb][l][t] : thread owns (l = tid>>4, 4 rows at 4*(tid&15)) ----
    {
        const int l  = tid >> 4;
        const int cc = tid & 15;
        float4 o;
        float* op = &o.x;
        #pragma unroll
        for (int j = 0; j < 4; ++j) {
            const int tok = 4 * cc + j;
            op[j] = red[0 * 1088 + tok * 17 + l] + red[1 * 1088 + tok * 17 + l]
                  + red[2 * 1088 + tok * 17 + l] + red[3 * 1088 + tok * 17 + l];
        }
        *reinterpret_cast<float4*>(
            &pbT[((size_t)(sb * 16 + l) << 13) + tset * 64 + 4 * cc]) = o;
    }
}

// ---------------- Kernel 2: Sinkhorn + fused finalize (R8 verbatim, KSB=8) ----------------
// 8 blocks x 256 thr, 4 contiguous rows/thread (c[4][16] in VGPRs).
// Prologue: coalesced pbT float4 reads. Per iter: dots -> butterfly ->
// s_wpart -> barrier -> 16 owners publish tagged u64; 128 lanes spin ONE
// entry each -> s_bpart -> barrier -> 16 owners sum 8 + write s_d1n ->
// barrier. Deterministic fixed-order sums, bitwise-stable replays.
__global__ __launch_bounds__(256) void k_sinkhorn(float* __restrict__ ws,
                                                  float* __restrict__ out) {
    unsigned long long* slab = reinterpret_cast<unsigned long long*>(ws + WS_SLAB);
    const float* pbT = ws + WS_PB;

    const int tid  = threadIdx.x;
    const int blk  = blockIdx.x;
    const int wv   = tid >> 6;                  // 0..3
    const int lane = tid & 63;

    // prologue: c[i][l] for rows blk*1024 + 4*tid + i
    float c[4][16];
    #pragma unroll
    for (int i = 0; i < 4; ++i)
        #pragma unroll
        for (int l = 0; l < 16; ++l) c[i][l] = 0.f;

    #pragma unroll
    for (int sb = 0; sb < KSB; ++sb) {
        #pragma unroll
        for (int l = 0; l < 16; ++l) {
            const float4 v = *reinterpret_cast<const float4*>(
                pbT + ((size_t)(sb * 16 + l) << 13) + blk * 1024 + 4 * tid);
            c[0][l] += v.x; c[1][l] += v.y; c[2][l] += v.z; c[3][l] += v.w;
        }
    }
    #pragma unroll
    for (int i = 0; i < 4; ++i)
        #pragma unroll
        for (int l = 0; l < 16; ++l) c[i][l] = expf(c[i][l]);

    float d1[16];
    #pragma unroll
    for (int l = 0; l < 16; ++l) d1[l] = 1.f;

    __shared__ float s_wpart[4][16];
    __shared__ float s_bpart[NBLK2][16];
    __shared__ float s_d1n[16];

    float d0n[4] = {0.f, 0.f, 0.f, 0.f};
    float err = 1e9f;
    int it = 0;

    do {
        // d0n per row
        #pragma unroll
        for (int i = 0; i < 4; ++i) {
            float s = 0.f;
            #pragma unroll
            for (int l = 0; l < 16; ++l) s += c[i][l] * d1[l];
            d0n[i] = (1.f / (float)T_TOK) / (s + 1e-8f);
        }

        // per-lane column partials over the 4 rows
        float con[16];
        #pragma unroll
        for (int l = 0; l < 16; ++l)
            con[l] = d0n[0] * c[0][l] + d0n[1] * c[1][l]
                   + d0n[2] * c[2][l] + d0n[3] * c[3][l];
        #pragma unroll
        for (int m = 1; m < 64; m <<= 1) {
            #pragma unroll
            for (int l = 0; l < 16; ++l) con[l] += __shfl_xor(con[l], m, 64);
        }
        if (lane == 0) {
            #pragma unroll
            for (int l = 0; l < 16; ++l) s_wpart[wv][l] = con[l];
        }
        __syncthreads();

        const int p = it & 1;
        if (tid < 16) {
            const float bs = s_wpart[0][tid] + s_wpart[1][tid]
                           + s_wpart[2][tid] + s_wpart[3][tid];
            const unsigned long long pv =
                ((unsigned long long)(unsigned)it << 32) |
                (unsigned long long)__float_as_uint(bs);
            __hip_atomic_store(&slab[(size_t)p * 128 + blk * 16 + tid],
                               pv, __ATOMIC_RELAXED, __HIP_MEMORY_SCOPE_AGENT);
        }
        if (tid < NBLK2 * 16) {
            // lane-parallel spin: ONE entry per lane
            unsigned long long v;
            int spins = 0;
            do {
                v = __hip_atomic_load(&slab[(size_t)p * 128 + tid],
                                      __ATOMIC_RELAXED, __HIP_MEMORY_SCOPE_AGENT);
            } while ((unsigned)(v >> 32) != (unsigned)it && ++spins < (1 << 22));
            s_bpart[tid >> 4][tid & 15] = __uint_as_float((unsigned)(v & 0xffffffffull));
        }
        __syncthreads();

        if (tid < 16) {
            float tot = 0.f;
            #pragma unroll
            for (int b = 0; b < NBLK2; ++b) tot += s_bpart[b][tid];
            s_d1n[tid] = (1.f / (float)L_DIM) / (tot + 1e-8f);
        }
        __syncthreads();

        float esum = 0.f;
        #pragma unroll
        for (int l = 0; l < 16; ++l) {
            const float nv = s_d1n[l];
            esum += fabsf(d1[l] - nv);
            d1[l] = nv;
        }
        err = esum * (1.f / 16.f);
        ++it;
    } while (err > 1e-4f && it < 512);

    // fused finalize per row: top-2 of (d1*c)*d0n, softmax-gather (ref op order)
    #pragma unroll
    for (int i = 0; i < 4; ++i) {
        const int t = blk * 1024 + 4 * tid + i;
        float v1 = -__builtin_inff(), v2 = -__builtin_inff();
        float a1 = 0.f, a2 = 0.f;
        int   i1 = 0, i2 = 0;
        float ssum = 0.f;
        #pragma unroll
        for (int l = 0; l < 16; ++l) {
            ssum += c[i][l];
            const float nv = (d1[l] * c[i][l]) * d0n[i];
            if (nv > v1) { v2 = v1; i2 = i1; a2 = a1; v1 = nv; i1 = l; a1 = c[i][l]; }
            else if (nv > v2) { v2 = nv; i2 = l; a2 = c[i][l]; }
        }
        out[(size_t)t * 2 + 0] = a1 / ssum;
        out[(size_t)t * 2 + 1] = a2 / ssum;
        out[(size_t)2 * T_TOK + (size_t)t * 2 + 0] = (float)i1;
        out[(size_t)2 * T_TOK + (size_t)t * 2 + 1] = (float)i2;
    }
}

extern "C" void kernel_launch(void* const* d_in, const int* in_sizes, int n_in,
                              void* d_out, int out_size, void* d_ws, size_t ws_size,
                              hipStream_t stream) {
    const float* x   = (const float*)d_in[0];
    const float* w1  = (const float*)d_in[1];
    const int*   tpe = (const int*)d_in[2];
    float* ws  = (float*)d_ws;
    float* out = (float*)d_out;

    // K1: tile-GEMM logits partials, transposed output (two 128-h passes/block)
    k1a<<<dim3(128 * KSB), dim3(256), 0, stream>>>(x, w1, tpe, ws + WS_PB);

    // K2: coalesced pbT prologue + sinkhorn + finalize (cooperative for
    // co-residency; sync is the one-sided tagged slab, no grid.sync)
    {
        void* args[] = { (void*)&ws, (void*)&out };
        hipLaunchCooperativeKernel((void*)k_sinkhorn, dim3(NBLK2), dim3(BLK2),
                                   args, 0, stream);
    }
}